// Round 12
// baseline (233.753 us; speedup 1.0000x reference)
//
#include <hip/hip_runtime.h>
#include <math.h>

#define NT 32768
#define DIM 2048
#define NE 64
#define RSCALE 2.5f
#define REPS 1e-20f
#define KC 32
#define NCH (DIM / KC)          // 64 global chunks
#define NSPLIT 4
#define KSEG (DIM / NSPLIT)     // 512 K per wave
#define NCHS (KSEG / KC)        // 16 chunks per wave
#define TOKB 16                 // tokens per block (and per wave)

typedef __attribute__((ext_vector_type(8))) short short8x;
typedef __attribute__((ext_vector_type(4))) float f32x4;
typedef __attribute__((ext_vector_type(4))) unsigned int uint4x;

// W bf16 limb planes, fragment-shaped: WLf[limb][chunk][expert-tile][lane] = 16 B.
// lane l: expert = et*16 + (l&15), k-octet = l>>4. 768 KB, L2-resident. (R7-verified)
__device__ short8x WLf[3][NCH][4][64];

// pack hi16 of two fp32 into one dword (low half = even element)
#define PACKHI(odd, even) __builtin_amdgcn_perm((odd), (even), 0x07060302u)

__device__ __forceinline__ void decomp4(f32x4 x, unsigned int o[6]) {
    unsigned int u0 = __float_as_uint(x.x), u1 = __float_as_uint(x.y);
    unsigned int u2 = __float_as_uint(x.z), u3 = __float_as_uint(x.w);
    o[0] = PACKHI(u1, u0); o[1] = PACKHI(u3, u2);
    float r0 = x.x - __uint_as_float(u0 & 0xffff0000u);
    float r1 = x.y - __uint_as_float(u1 & 0xffff0000u);
    float r2 = x.z - __uint_as_float(u2 & 0xffff0000u);
    float r3 = x.w - __uint_as_float(u3 & 0xffff0000u);
    unsigned int v0 = __float_as_uint(r0), v1 = __float_as_uint(r1);
    unsigned int v2 = __float_as_uint(r2), v3 = __float_as_uint(r3);
    o[2] = PACKHI(v1, v0); o[3] = PACKHI(v3, v2);
    float s0 = r0 - __uint_as_float(v0 & 0xffff0000u);
    float s1 = r1 - __uint_as_float(v1 & 0xffff0000u);
    float s2 = r2 - __uint_as_float(v2 & 0xffff0000u);
    float s3 = r3 - __uint_as_float(v3 & 0xffff0000u);
    o[4] = PACKHI(__float_as_uint(s1), __float_as_uint(s0));
    o[5] = PACKHI(__float_as_uint(s3), __float_as_uint(s2));
}

__device__ __forceinline__ void decomp8(f32x4 a, f32x4 b,
                                        short8x* f0, short8x* f1, short8x* f2) {
    unsigned int oa[6], ob[6];
    decomp4(a, oa); decomp4(b, ob);
    uint4x t0 = {oa[0], oa[1], ob[0], ob[1]};
    uint4x t1 = {oa[2], oa[3], ob[2], ob[3]};
    uint4x t2 = {oa[4], oa[5], ob[4], ob[5]};
    *f0 = __builtin_bit_cast(short8x, t0);
    *f1 = __builtin_bit_cast(short8x, t1);
    *f2 = __builtin_bit_cast(short8x, t2);
}

// pre-pass: decompose W into fragment-shaped limb planes. 64 blocks x 256. (R7-verified)
__global__ void decomp_w_kernel(const float* __restrict__ W) {
    const int ch = blockIdx.x;
    const int et = threadIdx.x >> 6;
    const int l  = threadIdx.x & 63;
    const float* src = W + (size_t)(et * 16 + (l & 15)) * DIM + ch * KC + (l >> 4) * 8;
    f32x4 lo = *(const f32x4*)src;
    f32x4 hi = *(const f32x4*)(src + 4);
    short8x f0, f1, f2;
    decomp8(lo, hi, &f0, &f1, &f2);
    WLf[0][ch][et][l] = f0;
    WLf[1][ch][et][l] = f1;
    WLf[2][ch][et][l] = f2;
}

// main: 2048 blocks x 256 threads (4 waves). Block = 16 tokens; wave w = K-split w
// (chunks w*16..w*16+15). Wave = 16 tok x 64 exp: 1 A-tile, 4 B-tiles, 24 MFMA/chunk.
// Barrier-free main loop: A direct from H (coalesced row-gather), B direct from WLf (L2).
// Per-(t,e) product set/order and 8-chunk fp64 drain windows bit-identical to the
// passing kernels; cross-split fp64 fold via LDS at the end.
__global__ __launch_bounds__(256, 4) void router_gemm(
    const float* __restrict__ H,
    const float* __restrict__ B,
    float* __restrict__ out)
{
    __shared__ double mdbuf[3][16][64];   // waves 1-3 partial masters
    __shared__ float scf[TOKB * 65];
    __shared__ float bsf[NE];

    const int tid  = threadIdx.x;
    const int lane = tid & 63;
    const int s    = __builtin_amdgcn_readfirstlane(tid >> 6);   // K-split 0..3
    const int l15  = lane & 15, g = lane >> 4;
    const size_t tb = (size_t)blockIdx.x * TOKB;

    if (tid < NE) bsf[tid] = B[tid];

    // lane l reads H[token = tb + (l&15)][kb + (l>>4)*8 .. +7]
    const float* hsrc = H + (tb + (size_t)l15) * DIM + s * KSEG + g * 8;

    f32x4 Cm[4], Cc[4];
    double md[4][4];
    #pragma unroll
    for (int et = 0; et < 4; ++et) {
        Cm[et] = (f32x4)0.0f; Cc[et] = (f32x4)0.0f;
        #pragma unroll
        for (int r = 0; r < 4; ++r) md[et][r] = 0.0;
    }

    f32x4 aLo = *(const f32x4*)hsrc;
    f32x4 aHi = *(const f32x4*)(hsrc + 4);

    #pragma unroll 2
    for (int c = 0; c < NCHS; ++c) {
        // prefetch next chunk's A (clamped on last iter; value unused)
        const float* np = hsrc + ((c + 1 < NCHS) ? (c + 1) : c) * KC;
        f32x4 nLo = *(const f32x4*)np;
        f32x4 nHi = *(const f32x4*)(np + 4);

        short8x a0, a1, a2;
        decomp8(aLo, aHi, &a0, &a1, &a2);

        const int ch = s * NCHS + c;      // global chunk
        #pragma unroll
        for (int et = 0; et < 4; ++et) {
            short8x b0 = WLf[0][ch][et][lane];
            short8x b1 = WLf[1][ch][et][lane];
            short8x b2 = WLf[2][ch][et][lane];
            Cm[et] = __builtin_amdgcn_mfma_f32_16x16x32_bf16(a0, b0, Cm[et], 0, 0, 0);
            Cc[et] = __builtin_amdgcn_mfma_f32_16x16x32_bf16(a1, b0, Cc[et], 0, 0, 0);
            Cc[et] = __builtin_amdgcn_mfma_f32_16x16x32_bf16(a2, b0, Cc[et], 0, 0, 0);
            Cc[et] = __builtin_amdgcn_mfma_f32_16x16x32_bf16(a0, b1, Cc[et], 0, 0, 0);
            Cc[et] = __builtin_amdgcn_mfma_f32_16x16x32_bf16(a1, b1, Cc[et], 0, 0, 0);
            Cc[et] = __builtin_amdgcn_mfma_f32_16x16x32_bf16(a0, b2, Cc[et], 0, 0, 0);
        }

        // fp64 drain at local chunks 7,15 = global chunks 8g+7 (same windows as before)
        if ((c & 7) == 7) {
            #pragma unroll
            for (int et = 0; et < 4; ++et) {
                #pragma unroll
                for (int r = 0; r < 4; ++r)
                    md[et][r] += (double)Cm[et][r] + (double)Cc[et][r];
                Cm[et] = (f32x4)0.0f; Cc[et] = (f32x4)0.0f;
            }
        }
        aLo = nLo; aHi = nHi;
    }

    // cross-split fp64 fold via LDS: waves 1-3 write, wave 0 folds in split order
    if (s != 0) {
        #pragma unroll
        for (int et = 0; et < 4; ++et)
            #pragma unroll
            for (int r = 0; r < 4; ++r)
                mdbuf[s - 1][et * 4 + r][lane] = md[et][r];
    }
    __syncthreads();

    if (s == 0) {
        #pragma unroll
        for (int et = 0; et < 4; ++et)
            #pragma unroll
            for (int r = 0; r < 4; ++r) {
                double m = ((md[et][r] + mdbuf[0][et * 4 + r][lane])
                          + mdbuf[1][et * 4 + r][lane]) + mdbuf[2][et * 4 + r][lane];
                float sc = 1.0f / (1.0f + expf(-(float)m));
                int t = g * 4 + r;                // C layout row
                int e = et * 16 + l15;            // C layout col
                scf[t * 65 + e] = sc;
            }
    }
    __syncthreads();

    // grouped top-k, one token per active thread (16 tokens over 4 waves)
    if ((tid & 15) == 0) {
        const int t = tid >> 4;
        const float* sc = &scf[t * 65];
        float gs[8];
        #pragma unroll
        for (int gg = 0; gg < 8; ++gg) {
            float m1 = -1e30f, m2 = -1e30f;
            #pragma unroll
            for (int j = 0; j < 8; ++j) {
                float v = sc[gg * 8 + j] + bsf[gg * 8 + j];
                if (v > m1) { m2 = m1; m1 = v; }
                else if (v > m2) { m2 = v; }
            }
            gs[gg] = m1 + m2;
        }
        unsigned gmask = 0;
        for (int i = 0; i < 4; ++i) {
            float best = -1e30f; int bg = 0;
            for (int gg = 0; gg < 8; ++gg)
                if (!((gmask >> gg) & 1u) && gs[gg] > best) { best = gs[gg]; bg = gg; }
            gmask |= 1u << bg;
        }
        unsigned long long picked = 0ull;
        int   idxs[8];
        float wts[8];
        float wsum = 0.0f;
        for (int i = 0; i < 8; ++i) {
            float best = -1e30f; int bi = 0;
            for (int e = 0; e < 64; ++e) {
                if ((picked >> e) & 1ull) continue;
                float v = ((gmask >> (e >> 3)) & 1u) ? (sc[e] + bsf[e]) : 0.0f;
                if (v > best) { best = v; bi = e; }
            }
            picked |= 1ull << bi;
            idxs[i] = bi;
            wts[i] = sc[bi];
            wsum += sc[bi];
        }
        const float scale = RSCALE / (wsum + REPS);
        const size_t token = tb + t;
        #pragma unroll
        for (int i = 0; i < 8; ++i) {
            out[token * 8 + i] = (float)idxs[i];
            out[(size_t)NT * 8 + token * 8 + i] = wts[i] * scale;
        }
    }
}

extern "C" void kernel_launch(void* const* d_in, const int* in_sizes, int n_in,
                              void* d_out, int out_size, void* d_ws, size_t ws_size,
                              hipStream_t stream) {
    (void)in_sizes; (void)n_in; (void)out_size; (void)d_ws; (void)ws_size;
    const float* H = (const float*)d_in[0];
    const float* W = (const float*)d_in[1];
    const float* B = (const float*)d_in[2];
    float* out = (float*)d_out;
    decomp_w_kernel<<<dim3(NCH), dim3(256), 0, stream>>>(W);
    router_gemm<<<dim3(NT / TOKB), dim3(256), 0, stream>>>(H, B, out);
}

// Round 13
// 148.860 us; speedup vs baseline: 1.5703x; 1.5703x over previous
//
#include <hip/hip_runtime.h>
#include <math.h>

#define NT 32768
#define DIM 2048
#define NE 64
#define RSCALE 2.5f
#define REPS 1e-20f
#define KC 64                    // K per chunk (64 = 2 kk-slices of 32)
#define NCHK (DIM / KC)          // 32 chunks
#define TOKB 32                  // tokens per block

// LDS (bytes): HL[3][32 rows][128] : 0..12287 ; WL[3][64 rows][128] : 12288..36863
// epilogue alias: scf f32[32][65] at 0 ; bsf f32[64] at 36864 (never aliased)
#define WL_OFF 12288
#define BS_OFF 36864
#define ARENA 37120

typedef __attribute__((ext_vector_type(8))) short short8x;
typedef __attribute__((ext_vector_type(4))) float f32x4;
typedef __attribute__((ext_vector_type(4))) unsigned int uint4x;

#define PACKHI(odd, even) __builtin_amdgcn_perm((odd), (even), 0x07060302u)

__device__ __forceinline__ void decomp4(f32x4 x, unsigned int o[6]) {
    unsigned int u0 = __float_as_uint(x.x), u1 = __float_as_uint(x.y);
    unsigned int u2 = __float_as_uint(x.z), u3 = __float_as_uint(x.w);
    o[0] = PACKHI(u1, u0); o[1] = PACKHI(u3, u2);
    float r0 = x.x - __uint_as_float(u0 & 0xffff0000u);
    float r1 = x.y - __uint_as_float(u1 & 0xffff0000u);
    float r2 = x.z - __uint_as_float(u2 & 0xffff0000u);
    float r3 = x.w - __uint_as_float(u3 & 0xffff0000u);
    unsigned int v0 = __float_as_uint(r0), v1 = __float_as_uint(r1);
    unsigned int v2 = __float_as_uint(r2), v3 = __float_as_uint(r3);
    o[2] = PACKHI(v1, v0); o[3] = PACKHI(v3, v2);
    float s0 = r0 - __uint_as_float(v0 & 0xffff0000u);
    float s1 = r1 - __uint_as_float(v1 & 0xffff0000u);
    float s2 = r2 - __uint_as_float(v2 & 0xffff0000u);
    float s3 = r3 - __uint_as_float(v3 & 0xffff0000u);
    o[4] = PACKHI(__float_as_uint(s1), __float_as_uint(s0));
    o[5] = PACKHI(__float_as_uint(s3), __float_as_uint(s2));
}

__device__ __forceinline__ void decomp8(f32x4 a, f32x4 b,
                                        short8x* f0, short8x* f1, short8x* f2) {
    unsigned int oa[6], ob[6];
    decomp4(a, oa); decomp4(b, ob);
    uint4x t0 = {oa[0], oa[1], ob[0], ob[1]};
    uint4x t1 = {oa[2], oa[3], ob[2], ob[3]};
    uint4x t2 = {oa[4], oa[5], ob[4], ob[5]};
    *f0 = __builtin_bit_cast(short8x, t0);
    *f1 = __builtin_bit_cast(short8x, t1);
    *f2 = __builtin_bit_cast(short8x, t2);
}

// lgkm-only barrier: LDS committed, global loads stay in flight
#define BARRIER() do { \
    asm volatile("s_waitcnt lgkmcnt(0)" ::: "memory"); \
    __builtin_amdgcn_s_barrier(); \
    __builtin_amdgcn_sched_barrier(0); \
} while (0)

// issue chunk (KOFF floats) loads: H octet (f32x8) + W 16-float run (f32x16)
#define STAGE_ISSUE(H0, H1, W0, W1, W2, W3, KOFF) do { \
    H0 = *(const f32x4*)(hgsrc + (KOFF)); \
    H1 = *(const f32x4*)(hgsrc + (KOFF) + 4); \
    W0 = *(const f32x4*)(wgsrc + (KOFF)); \
    W1 = *(const f32x4*)(wgsrc + (KOFF) + 4); \
    W2 = *(const f32x4*)(wgsrc + (KOFF) + 8); \
    W3 = *(const f32x4*)(wgsrc + (KOFF) + 12); \
} while (0)

// decompose staged regs, write H (1 octet) + W (2 octets) limb slots
#define STAGE_WRITE(H0, H1, W0, W1, W2, W3) do { \
    short8x f0_, f1_, f2_; \
    decomp8(H0, H1, &f0_, &f1_, &f2_); \
    *(short8x*)(arena + 0    + hoff) = f0_; \
    *(short8x*)(arena + 4096 + hoff) = f1_; \
    *(short8x*)(arena + 8192 + hoff) = f2_; \
    decomp8(W0, W1, &f0_, &f1_, &f2_); \
    *(short8x*)(arena + WL_OFF + 0     + woff0) = f0_; \
    *(short8x*)(arena + WL_OFF + 8192  + woff0) = f1_; \
    *(short8x*)(arena + WL_OFF + 16384 + woff0) = f2_; \
    decomp8(W2, W3, &f0_, &f1_, &f2_); \
    *(short8x*)(arena + WL_OFF + 0     + woff1) = f0_; \
    *(short8x*)(arena + WL_OFF + 8192  + woff1) = f1_; \
    *(short8x*)(arena + WL_OFF + 16384 + woff1) = f2_; \
} while (0)

// wave = 32 tok x 16 exp (et = wave id) over this chunk's 64 K (2 kk-slices).
// Per-(t,e) limb-product order identical to the passing kernels.
#define COMPUTE() do { \
    _Pragma("unroll") \
    for (int kk = 0; kk < 2; ++kk) { \
        short8x a0[2], a1[2], a2[2]; \
        _Pragma("unroll") \
        for (int tt = 0; tt < 2; ++tt) { \
            const int r_ = tt * 16 + l15; \
            const int sb = r_ * 128 + (((kk * 4 + g) ^ (r_ & 7)) << 4); \
            a0[tt] = *(const short8x*)(arena + 0    + sb); \
            a1[tt] = *(const short8x*)(arena + 4096 + sb); \
            a2[tt] = *(const short8x*)(arena + 8192 + sb); \
        } \
        const int rw = w * 16 + l15; \
        const int wb = rw * 128 + (((kk * 4 + g) ^ (rw & 7)) << 4); \
        short8x b0 = *(const short8x*)(arena + WL_OFF + 0     + wb); \
        short8x b1 = *(const short8x*)(arena + WL_OFF + 8192  + wb); \
        short8x b2 = *(const short8x*)(arena + WL_OFF + 16384 + wb); \
        _Pragma("unroll") \
        for (int tt = 0; tt < 2; ++tt) { \
            Cm[tt] = __builtin_amdgcn_mfma_f32_16x16x32_bf16(a0[tt], b0, Cm[tt], 0, 0, 0); \
            Cc[tt] = __builtin_amdgcn_mfma_f32_16x16x32_bf16(a1[tt], b0, Cc[tt], 0, 0, 0); \
            Cc[tt] = __builtin_amdgcn_mfma_f32_16x16x32_bf16(a2[tt], b0, Cc[tt], 0, 0, 0); \
            Cc[tt] = __builtin_amdgcn_mfma_f32_16x16x32_bf16(a0[tt], b1, Cc[tt], 0, 0, 0); \
            Cc[tt] = __builtin_amdgcn_mfma_f32_16x16x32_bf16(a1[tt], b1, Cc[tt], 0, 0, 0); \
            Cc[tt] = __builtin_amdgcn_mfma_f32_16x16x32_bf16(a0[tt], b2, Cc[tt], 0, 0, 0); \
        } \
    } \
} while (0)

#define DRAIN do { \
    _Pragma("unroll") \
    for (int tt = 0; tt < 2; ++tt) { \
        _Pragma("unroll") \
        for (int r = 0; r < 4; ++r) \
            md[tt][r] += (double)Cm[tt][r] + (double)Cc[tt][r]; \
        Cm[tt] = (f32x4)0.0f; Cc[tt] = (f32x4)0.0f; \
    } \
} while (0)

// 1024 blocks x 256 threads (4 waves). Block = 32 tok x 64 exp; wave w = experts
// w*16..w*16+15 x all 32 tokens x full K. KC=64, single-buffered LDS (36 KB ->
// 4 blocks/CU = 4 independent barrier groups), depth-2 reg prefetch, lgkm barriers.
// fp32 window partials and fp64 drain windows bit-identical to the passing kernels.
__global__ __launch_bounds__(256, 4) void router_kernel(
    const float* __restrict__ H,
    const float* __restrict__ W,
    const float* __restrict__ B,
    float* __restrict__ out)
{
    __shared__ __align__(16) char arena[ARENA];
    float* bsf = (float*)(arena + BS_OFF);
    float* scf = (float*)(arena);          // epilogue alias over HL

    const int tid  = threadIdx.x;
    const int lane = tid & 63;
    const int w    = __builtin_amdgcn_readfirstlane(tid >> 6);   // wave = expert-tile
    const int l15  = lane & 15, g = lane >> 4;
    const size_t tb = (size_t)blockIdx.x * TOKB;

    if (tid < NE) bsf[tid] = B[tid];

    // staging roles: H octet: row = tid>>3 (0..31), octet hq = tid&7
    //                W run:   row = tid>>2 (0..63), octets wq, wq+1 (wq = (tid&3)*2)
    const int hrow = tid >> 3, hq = tid & 7;
    const int wrow = tid >> 2, wq = (tid & 3) << 1;
    const float* hgsrc = H + (tb + (size_t)hrow) * DIM + hq * 8;
    const float* wgsrc = W + (size_t)wrow * DIM + wq * 8;
    const int hoff  = hrow * 128 + ((hq ^ (hrow & 7)) << 4);
    const int woff0 = wrow * 128 + ((wq ^ (wrow & 7)) << 4);
    const int woff1 = wrow * 128 + (((wq + 1) ^ (wrow & 7)) << 4);

    f32x4 Cm[2], Cc[2];
    double md[2][4];
    #pragma unroll
    for (int tt = 0; tt < 2; ++tt) {
        Cm[tt] = (f32x4)0.0f; Cc[tt] = (f32x4)0.0f;
        #pragma unroll
        for (int r = 0; r < 4; ++r) md[tt][r] = 0.0;
    }

    f32x4 hA0, hA1, wA0, wA1, wA2, wA3;
    f32x4 hB0, hB1, wB0, wB1, wB2, wB3;

    // prologue: issue chunks 0,1; write chunk 0
    STAGE_ISSUE(hA0, hA1, wA0, wA1, wA2, wA3, 0);
    STAGE_ISSUE(hB0, hB1, wB0, wB1, wB2, wB3, KC);
    STAGE_WRITE(hA0, hA1, wA0, wA1, wA2, wA3);
    BARRIER();

    for (int chb = 0; chb < NCHK; chb += 2) {
        // even chunk chb (in buf)
        COMPUTE();
        if (chb + 2 < NCHK) STAGE_ISSUE(hA0, hA1, wA0, wA1, wA2, wA3, (chb + 2) * KC);
        BARRIER();                                   // reads done
        STAGE_WRITE(hB0, hB1, wB0, wB1, wB2, wB3);   // chunk chb+1 -> buf
        BARRIER();                                   // writes visible

        // odd chunk chb+1
        COMPUTE();
        if (chb + 3 < NCHK) STAGE_ISSUE(hB0, hB1, wB0, wB1, wB2, wB3, (chb + 3) * KC);
        if (((chb + 1) & 3) == 3) DRAIN;             // every 4 chunks = 256 K windows
        BARRIER();                                   // reads done
        if (chb + 2 < NCHK) STAGE_WRITE(hA0, hA1, wA0, wA1, wA2, wA3);
        BARRIER();                                   // writes visible
    }

    // sigmoid scores -> scf (aliases HL; all LDS reads completed at last barrier)
    #pragma unroll
    for (int tt = 0; tt < 2; ++tt)
        #pragma unroll
        for (int r = 0; r < 4; ++r) {
            float logit = (float)md[tt][r];
            float s = 1.0f / (1.0f + expf(-logit));
            int t = tt * 16 + g * 4 + r;
            int e = w * 16 + l15;
            scf[t * 65 + e] = s;
        }
    __syncthreads();

    // grouped top-k, one token per active thread (32 tokens over 4 waves)
    if ((tid & 7) == 0) {
        const int t = tid >> 3;
        const float* sc = &scf[t * 65];
        float gs[8];
        #pragma unroll
        for (int gg = 0; gg < 8; ++gg) {
            float m1 = -1e30f, m2 = -1e30f;
            #pragma unroll
            for (int j = 0; j < 8; ++j) {
                float v = sc[gg * 8 + j] + bsf[gg * 8 + j];
                if (v > m1) { m2 = m1; m1 = v; }
                else if (v > m2) { m2 = v; }
            }
            gs[gg] = m1 + m2;
        }
        unsigned gmask = 0;
        for (int i = 0; i < 4; ++i) {
            float best = -1e30f; int bg = 0;
            for (int gg = 0; gg < 8; ++gg)
                if (!((gmask >> gg) & 1u) && gs[gg] > best) { best = gs[gg]; bg = gg; }
            gmask |= 1u << bg;
        }
        unsigned long long picked = 0ull;
        int   idxs[8];
        float wts[8];
        float wsum = 0.0f;
        for (int i = 0; i < 8; ++i) {
            float best = -1e30f; int bi = 0;
            for (int e = 0; e < 64; ++e) {
                if ((picked >> e) & 1ull) continue;
                float v = ((gmask >> (e >> 3)) & 1u) ? (sc[e] + bsf[e]) : 0.0f;
                if (v > best) { best = v; bi = e; }
            }
            picked |= 1ull << bi;
            idxs[i] = bi;
            wts[i] = sc[bi];
            wsum += sc[bi];
        }
        const float scale = RSCALE / (wsum + REPS);
        const size_t token = tb + t;
        #pragma unroll
        for (int i = 0; i < 8; ++i) {
            out[token * 8 + i] = (float)idxs[i];
            out[(size_t)NT * 8 + token * 8 + i] = wts[i] * scale;
        }
    }
}

extern "C" void kernel_launch(void* const* d_in, const int* in_sizes, int n_in,
                              void* d_out, int out_size, void* d_ws, size_t ws_size,
                              hipStream_t stream) {
    (void)in_sizes; (void)n_in; (void)out_size; (void)d_ws; (void)ws_size;
    const float* H = (const float*)d_in[0];
    const float* W = (const float*)d_in[1];
    const float* B = (const float*)d_in[2];
    float* out = (float*)d_out;
    router_kernel<<<dim3(NT / TOKB), dim3(256), 0, stream>>>(H, W, B, out);
}

// Round 14
// 123.797 us; speedup vs baseline: 1.8882x; 1.2024x over previous
//
#include <hip/hip_runtime.h>
#include <math.h>

#define NT 32768
#define DIM 2048
#define NE 64
#define RSCALE 2.5f
#define REPS 1e-20f
#define KC 32
#define NCH (DIM / KC)
#define TOK 64

// LDS arena (bytes):
//   HL[2][3][64 tok][4 slots x 16B]  : 0     .. 24575   (H bf16 limb planes, dbuf)
//   WL[2][3][64 exp][4 slots x 16B]  : 24576 .. 49151   (W bf16 limb planes, dbuf)
//   Bs[64] f32                       : 49152 .. 49407
//   Sc[64][65] f32                   : alias at 0 (epilogue only)
#define HL_BUF 12288
#define WL_OFF 24576
#define BS_OFF 49152
#define ARENA 49408

typedef const __attribute__((address_space(1))) void GV;
typedef __attribute__((address_space(3))) void LV;
typedef __attribute__((ext_vector_type(8))) short short8x;
typedef __attribute__((ext_vector_type(4))) float f32x4;
typedef __attribute__((ext_vector_type(4))) unsigned int uint4x;

// W limb image, pre-decomposed and pre-swizzled: per chunk a 12 KB block that is
// byte-identical to what the R9 kernel's W STAGE_WRITE produced in LDS.
__device__ __align__(16) char WImg[NCH][3 * 4096];

// pack hi16 of two fp32 into one dword (low half = even element)
#define PACKHI(odd, even) __builtin_amdgcn_perm((odd), (even), 0x07060302u)

__device__ __forceinline__ void decomp4(f32x4 x, unsigned int o[6]) {
    unsigned int u0 = __float_as_uint(x.x), u1 = __float_as_uint(x.y);
    unsigned int u2 = __float_as_uint(x.z), u3 = __float_as_uint(x.w);
    o[0] = PACKHI(u1, u0); o[1] = PACKHI(u3, u2);
    float r0 = x.x - __uint_as_float(u0 & 0xffff0000u);
    float r1 = x.y - __uint_as_float(u1 & 0xffff0000u);
    float r2 = x.z - __uint_as_float(u2 & 0xffff0000u);
    float r3 = x.w - __uint_as_float(u3 & 0xffff0000u);
    unsigned int v0 = __float_as_uint(r0), v1 = __float_as_uint(r1);
    unsigned int v2 = __float_as_uint(r2), v3 = __float_as_uint(r3);
    o[2] = PACKHI(v1, v0); o[3] = PACKHI(v3, v2);
    float s0 = r0 - __uint_as_float(v0 & 0xffff0000u);
    float s1 = r1 - __uint_as_float(v1 & 0xffff0000u);
    float s2 = r2 - __uint_as_float(v2 & 0xffff0000u);
    float s3 = r3 - __uint_as_float(v3 & 0xffff0000u);
    o[4] = PACKHI(__float_as_uint(s1), __float_as_uint(s0));
    o[5] = PACKHI(__float_as_uint(s3), __float_as_uint(s2));
}

__device__ __forceinline__ void decomp8(f32x4 a, f32x4 b,
                                        short8x* f0, short8x* f1, short8x* f2) {
    unsigned int oa[6], ob[6];
    decomp4(a, oa); decomp4(b, ob);
    uint4x t0 = {oa[0], oa[1], ob[0], ob[1]};
    uint4x t1 = {oa[2], oa[3], ob[2], ob[3]};
    uint4x t2 = {oa[4], oa[5], ob[4], ob[5]};
    *f0 = __builtin_bit_cast(short8x, t0);
    *f1 = __builtin_bit_cast(short8x, t1);
    *f2 = __builtin_bit_cast(short8x, t2);
}

// pre-pass: decompose W once into the LDS-image layout (same limb values and same
// swizzled slot bytes as the R9 kernel's in-loop W staging). 64 blocks x 256.
__global__ void prep_w_kernel(const float* __restrict__ W) {
    const int ch = blockIdx.x;
    const int tid = threadIdx.x;
    const int srow = tid >> 2;          // expert row 0..63
    const int sq   = tid & 3;           // k-octet 0..3
    const float* src = W + (size_t)srow * DIM + ch * KC + sq * 8;
    f32x4 lo = *(const f32x4*)src;
    f32x4 hi = *(const f32x4*)(src + 4);
    short8x f0, f1, f2;
    decomp8(lo, hi, &f0, &f1, &f2);
    const int soff = srow * 64 + ((sq ^ ((srow >> 1) & 3)) << 4);
    *(short8x*)&WImg[ch][0 * 4096 + soff] = f0;
    *(short8x*)&WImg[ch][1 * 4096 + soff] = f1;
    *(short8x*)&WImg[ch][2 * 4096 + soff] = f2;
}

// H-only register staging (depth-2)
#define STAGE_ISSUE(HA, HB, KOFF) do { \
    HA = *(const f32x4*)(hgsrc + (KOFF)); \
    HB = *(const f32x4*)(hgsrc + (KOFF) + 4); \
} while (0)

#define STAGE_WRITE_H(HA, HB, PN) do { \
    short8x f0_, f1_, f2_; \
    decomp8(HA, HB, &f0_, &f1_, &f2_); \
    *(short8x*)(arena + (PN) * HL_BUF + 0 * 4096 + soff) = f0_; \
    *(short8x*)(arena + (PN) * HL_BUF + 1 * 4096 + soff) = f1_; \
    *(short8x*)(arena + (PN) * HL_BUF + 2 * 4096 + soff) = f2_; \
} while (0)

// W staging: direct L2 -> LDS DMA of the pre-baked image (zero VALU, zero ds_write).
// LDS dest base is wave-uniform; HW writes base + lane*16; global src is per-lane.
#define WSTAGE(CHN, PN) do { \
    const char* ws_ = WImg[(CHN)]; \
    __builtin_amdgcn_global_load_lds((GV*)(ws_ + 0 * 4096 + wgofs), \
        (LV*)(arena + WL_OFF + (PN) * HL_BUF + 0 * 4096 + wlofs), 16, 0, 0); \
    __builtin_amdgcn_global_load_lds((GV*)(ws_ + 1 * 4096 + wgofs), \
        (LV*)(arena + WL_OFF + (PN) * HL_BUF + 1 * 4096 + wlofs), 16, 0, 0); \
    __builtin_amdgcn_global_load_lds((GV*)(ws_ + 2 * 4096 + wgofs), \
        (LV*)(arena + WL_OFF + (PN) * HL_BUF + 2 * 4096 + wlofs), 16, 0, 0); \
} while (0)

// wave = 32 tok x 32 exp = 2x2 of 16x16 tiles; 12 b128 reads feed 24 MFMAs.
// Per-tile MFMA order identical to the passing kernels (bit-identical logits).
#define COMPUTE(P) do { \
    const char* hb = arena + (P) * HL_BUF; \
    const char* wb = arena + WL_OFF + (P) * HL_BUF; \
    short8x a0[2], a1[2], a2[2]; \
    _Pragma("unroll") \
    for (int tt = 0; tt < 2; ++tt) { \
        const int t_ = wr * 32 + tt * 16 + l15; \
        const int ro_ = t_ * 64 + ((g ^ ((t_ >> 1) & 3)) << 4); \
        a0[tt] = *(const short8x*)(hb + 0 * 4096 + ro_); \
        a1[tt] = *(const short8x*)(hb + 1 * 4096 + ro_); \
        a2[tt] = *(const short8x*)(hb + 2 * 4096 + ro_); \
    } \
    _Pragma("unroll") \
    for (int et = 0; et < 2; ++et) { \
        const int e_ = wc * 32 + et * 16 + l15; \
        const int ro_ = e_ * 64 + ((g ^ ((e_ >> 1) & 3)) << 4); \
        short8x b0 = *(const short8x*)(wb + 0 * 4096 + ro_); \
        short8x b1 = *(const short8x*)(wb + 1 * 4096 + ro_); \
        short8x b2 = *(const short8x*)(wb + 2 * 4096 + ro_); \
        _Pragma("unroll") \
        for (int tt = 0; tt < 2; ++tt) { \
            Cm[tt][et] = __builtin_amdgcn_mfma_f32_16x16x32_bf16(a0[tt], b0, Cm[tt][et], 0, 0, 0); \
            Cc[tt][et] = __builtin_amdgcn_mfma_f32_16x16x32_bf16(a1[tt], b0, Cc[tt][et], 0, 0, 0); \
            Cc[tt][et] = __builtin_amdgcn_mfma_f32_16x16x32_bf16(a2[tt], b0, Cc[tt][et], 0, 0, 0); \
            Cc[tt][et] = __builtin_amdgcn_mfma_f32_16x16x32_bf16(a0[tt], b1, Cc[tt][et], 0, 0, 0); \
            Cc[tt][et] = __builtin_amdgcn_mfma_f32_16x16x32_bf16(a1[tt], b1, Cc[tt][et], 0, 0, 0); \
            Cc[tt][et] = __builtin_amdgcn_mfma_f32_16x16x32_bf16(a0[tt], b2, Cc[tt][et], 0, 0, 0); \
        } \
    } \
} while (0)

#define DRAIN do { \
    _Pragma("unroll") \
    for (int tt = 0; tt < 2; ++tt) \
        _Pragma("unroll") \
        for (int et = 0; et < 2; ++et) { \
            _Pragma("unroll") \
            for (int r = 0; r < 4; ++r) \
                md[tt][et][r] += (double)Cm[tt][et][r] + (double)Cc[tt][et][r]; \
            Cm[tt][et] = (f32x4)0.0f; Cc[tt][et] = (f32x4)0.0f; \
        } \
} while (0)

// 512 blocks x 256 threads (4 waves). R9 structure: wave = 32x32 output, dbuf LDS,
// one barrier per chunk. W limbs arrive via global_load_lds from the pre-baked image
// (no W decompose, no W ds_writes in-loop); H staged in registers + decomposed once.
__global__ __launch_bounds__(256, 2) void router_kernel(
    const float* __restrict__ H,
    const float* __restrict__ B,
    float* __restrict__ out)
{
    __shared__ __align__(16) char arena[ARENA];
    float* bsf = (float*)(arena + BS_OFF);
    float* scf = (float*)(arena);

    const int tid  = threadIdx.x;
    const int lane = tid & 63;
    const int w    = __builtin_amdgcn_readfirstlane(tid >> 6);
    const int l15  = lane & 15, g = lane >> 4;
    const size_t tb = (size_t)blockIdx.x * TOK;

    if (tid < NE) bsf[tid] = B[tid];

    // H staging role: token row = tid>>2 (0..63), k-octet = tid&3
    const int srow = tid >> 2;
    const int sq   = tid & 3;
    const float* hgsrc = H + (tb + (size_t)srow) * DIM + sq * 8;
    const int soff = srow * 64 + ((sq ^ ((srow >> 1) & 3)) << 4);

    // W staging addresses: per-lane global offset, wave-uniform LDS offset
    const int wgofs = tid * 16;
    const int wlofs = w * 1024;

    // compute role: wave quadrant (32 tok x 32 exp)
    const int wr = w & 1, wc = w >> 1;

    f32x4 Cm[2][2], Cc[2][2];
    double md[2][2][4];
    #pragma unroll
    for (int tt = 0; tt < 2; ++tt)
        #pragma unroll
        for (int et = 0; et < 2; ++et) {
            Cm[tt][et] = (f32x4)0.0f; Cc[tt][et] = (f32x4)0.0f;
            #pragma unroll
            for (int r = 0; r < 4; ++r) md[tt][et][r] = 0.0;
        }

    f32x4 hA0, hA1, hB0, hB1;

    // prologue: W ch0 -> buf0 (DMA); H ch0 regs -> write buf0; H ch1 regs
    WSTAGE(0, 0);
    STAGE_ISSUE(hA0, hA1, 0);
    STAGE_WRITE_H(hA0, hA1, 0);
    STAGE_ISSUE(hB0, hB1, KC);
    __syncthreads();

    for (int chb = 0; chb < NCH; chb += 2) {
        // even chunk chb: read buf0; stage ch+1 -> buf1
        WSTAGE(chb + 1, 1);
        if (chb + 2 < NCH) STAGE_ISSUE(hA0, hA1, (chb + 2) * KC);
        COMPUTE(0);
        STAGE_WRITE_H(hB0, hB1, 1);
        __syncthreads();

        // odd chunk chb+1: read buf1; stage ch+2 -> buf0
        if (chb + 2 < NCH) {
            WSTAGE(chb + 2, 0);
            STAGE_ISSUE(hB0, hB1, (chb + 3 < NCH) ? (chb + 3) * KC : (chb + 2) * KC);
        }
        COMPUTE(1);
        if (chb + 2 < NCH) STAGE_WRITE_H(hA0, hA1, 0);
        if (((chb + 1) & 7) == 7) DRAIN;
        __syncthreads();
    }

    // sigmoid scores -> Sc (aliases dead limb planes; all reads done at last barrier)
    #pragma unroll
    for (int tt = 0; tt < 2; ++tt)
        #pragma unroll
        for (int et = 0; et < 2; ++et)
            #pragma unroll
            for (int r = 0; r < 4; ++r) {
                float logit = (float)md[tt][et][r];
                float s = 1.0f / (1.0f + expf(-logit));
                int t = wr * 32 + tt * 16 + g * 4 + r;
                int e = wc * 32 + et * 16 + l15;
                scf[t * 65 + e] = s;
            }
    __syncthreads();

    // grouped top-k, one token per active thread (64 tokens over 4 waves)
    if ((tid & 3) == 0) {
        const int t = tid >> 2;
        const float* sc = &scf[t * 65];
        float gs[8];
        #pragma unroll
        for (int gg = 0; gg < 8; ++gg) {
            float m1 = -1e30f, m2 = -1e30f;
            #pragma unroll
            for (int j = 0; j < 8; ++j) {
                float v = sc[gg * 8 + j] + bsf[gg * 8 + j];
                if (v > m1) { m2 = m1; m1 = v; }
                else if (v > m2) { m2 = v; }
            }
            gs[gg] = m1 + m2;
        }
        unsigned gmask = 0;
        for (int i = 0; i < 4; ++i) {
            float best = -1e30f; int bg = 0;
            for (int gg = 0; gg < 8; ++gg)
                if (!((gmask >> gg) & 1u) && gs[gg] > best) { best = gs[gg]; bg = gg; }
            gmask |= 1u << bg;
        }
        unsigned long long picked = 0ull;
        int   idxs[8];
        float wts[8];
        float wsum = 0.0f;
        for (int i = 0; i < 8; ++i) {
            float best = -1e30f; int bi = 0;
            for (int e = 0; e < 64; ++e) {
                if ((picked >> e) & 1ull) continue;
                float v = ((gmask >> (e >> 3)) & 1u) ? (sc[e] + bsf[e]) : 0.0f;
                if (v > best) { best = v; bi = e; }
            }
            picked |= 1ull << bi;
            idxs[i] = bi;
            wts[i] = sc[bi];
            wsum += sc[bi];
        }
        const float scale = RSCALE / (wsum + REPS);
        const size_t token = tb + t;
        #pragma unroll
        for (int i = 0; i < 8; ++i) {
            out[token * 8 + i] = (float)idxs[i];
            out[(size_t)NT * 8 + token * 8 + i] = wts[i] * scale;
        }
    }
}

extern "C" void kernel_launch(void* const* d_in, const int* in_sizes, int n_in,
                              void* d_out, int out_size, void* d_ws, size_t ws_size,
                              hipStream_t stream) {
    (void)in_sizes; (void)n_in; (void)out_size; (void)d_ws; (void)ws_size;
    const float* H = (const float*)d_in[0];
    const float* W = (const float*)d_in[1];
    const float* B = (const float*)d_in[2];
    float* out = (float*)d_out;
    prep_w_kernel<<<dim3(NCH), dim3(256), 0, stream>>>(W);
    router_kernel<<<dim3(NT / TOK), dim3(256), 0, stream>>>(H, B, out);
}